// Round 1
// baseline (791.773 us; speedup 1.0000x reference)
//
#include <hip/hip_runtime.h>
#include <hip/hip_fp16.h>
#include <cstdint>

#define T_STEPS 512
#define HDIM    256
#define ROWS    8
#define LN_EPS  1e-5f

typedef _Float16 half8   __attribute__((ext_vector_type(8)));
typedef _Float16 half4v  __attribute__((ext_vector_type(4)));
typedef float    float4v __attribute__((ext_vector_type(4)));

// LDS 47.6 KB. One barrier per step; NO global memory ops inside the t-loop
// (x is pre-converted to clamped int indices in LDS), so the barrier's
// s_waitcnt vmcnt(0) is free. Ah/Al/red double-buffered (read t&1, write
// (t+1)&1). 8 real rows; MFMA B-fragments read row (m&7): cols 8..15 of the
// 16-row tile are same-address broadcasts (free).
struct __align__(16) Smem {
  _Float16 Ah[2][8][264];   // 8448 B  g_hi = fp16(gamma*tanh)
  _Float16 Al[2][8][264];   // 8448 B  g_lo * 2^11
  float    gb[10][268];     // 10720 B gb[v][n] = tanh(v*we+be)@W + bu + beta@W
  float    wg[260];         // 1040 B  gamma @ W (deferred-LN mu term)
  float    wb[260];         // 1040 B  beta @ W
  float    red[2][8][20];   // 2560 B  LN partials: [buf][row][w]=S, [row][8+w]=Sq
  int      xi[8][516];      // 16512 B clamped x indices (+pad col for t+1 prefetch)
};

__device__ __forceinline__ float tanh_fast(float x) {
  float e = __expf(2.0f * x);
  float r = __builtin_amdgcn_rcpf(e + 1.0f);
  return fmaf(-2.0f, r, 1.0f);
}

__global__ __launch_bounds__(512, 1)
void rnn_scan_kernel(const float* __restrict__ x,
                     const float* __restrict__ we,  const float* __restrict__ be,
                     const float* __restrict__ Wu,  const float* __restrict__ bu,
                     const float* __restrict__ gma, const float* __restrict__ bta,
                     const float* __restrict__ Wo,  const float* __restrict__ bo,
                     float* __restrict__ out)
{
  __shared__ Smem sm;
  const int tid = threadIdx.x;
  const int wv  = tid >> 6;        // wave 0..7, owns n in [32*wv, 32*wv+32)
  const int l   = tid & 63;
  const int q   = l >> 4;
  const int m   = l & 15;
  const int sel = m >> 3;          // which of the wave's two n-subtiles this lane finalizes
  const int r   = m & 7;           // real batch row within tile
  const int r0  = blockIdx.x * ROWS;

  // ---- init 0: x -> clamped int indices in LDS (the ONLY x reads) ----
  for (int i = tid; i < ROWS * T_STEPS; i += 512) {
    const int rr = i >> 9, c = i & (T_STEPS - 1);
    int xv = (int)x[(size_t)(r0 + rr) * T_STEPS + c];
    xv = xv < 0 ? 0 : (xv > 9 ? 9 : xv);
    sm.xi[rr][c] = xv;
  }
  if (tid < ROWS) sm.xi[tid][T_STEPS] = 0;   // t+1 prefetch pad

  // ---- init 1: embed-tanh table in (to-be-zeroed) Ah/Al space ----
  float* et = reinterpret_cast<float*>(&sm.Ah[0][0][0]);   // 10240 B < 16896 B
  if (tid < HDIM) {
    const float wek = we[tid], bek = be[tid];
    #pragma unroll
    for (int v = 0; v < 10; ++v)
      et[v*HDIM + tid] = tanh_fast(fmaf((float)v, wek, bek));
  }
  __syncthreads();

  // ---- init 2: gb = et@W + bu ; wg = gamma@W ; wb = beta@W ----
  {
    const int g = tid >> 8;        // 0: v=0..4 + wg, 1: v=5..9 + wb
    const int n = tid & 255;
    float acc[5] = {0,0,0,0,0};
    float accx = 0.0f;
    const int vb = g * 5;
    for (int k = 0; k < HDIM; ++k) {
      const float wk = Wu[(size_t)k*HDIM + n];
      #pragma unroll
      for (int v = 0; v < 5; ++v) acc[v] = fmaf(et[(vb+v)*HDIM + k], wk, acc[v]);
      const float xk = g ? bta[k] : gma[k];
      accx = fmaf(xk, wk, accx);
    }
    const float bun = bu[n];
    #pragma unroll
    for (int v = 0; v < 5; ++v) sm.gb[vb+v][n] = acc[v] + bun;
    if (g == 0) sm.wg[n] = accx; else sm.wb[n] = accx;
  }
  __syncthreads();

  // ---- init 3: fold beta@W into gb (beta==0 here; kept general), zero bufs ----
  if (tid < HDIM) {
    const float wbn = sm.wb[tid];
    #pragma unroll
    for (int v = 0; v < 10; ++v) sm.gb[v][tid] += wbn;
  }
  {
    // Ah+Al, BOTH buffers = 8448 halves = 4224 dwords. (R3 bug: 8448 dwords
    // overran into gb and zeroed the bias tables.)
    uint32_t* p = reinterpret_cast<uint32_t*>(&sm.Ah[0][0][0]);
    for (int i = tid; i < 4224; i += 512) p[i] = 0u;
  }
  if (tid < 320) (&sm.red[0][0][0])[tid] = 0.0f;

  // ---- persistent W fragments: full K, this wave's two 16-wide n-tiles ----
  // A'[n][k]: lane holds n = 32*wv + nt*16 + m, k = kt*32 + q*8 + j (128 regs)
  half8 Whi[2][8], Wlo[2][8];
  #pragma unroll
  for (int nt = 0; nt < 2; ++nt) {
    const int n = wv*32 + nt*16 + m;
    #pragma unroll
    for (int kt = 0; kt < 8; ++kt) {
      const int k0 = kt*32 + q*8;
      half8 hi, lo;
      #pragma unroll
      for (int j = 0; j < 8; ++j) {
        float v = Wu[(size_t)(k0 + j)*HDIM + n];           // L2-hot across blocks
        _Float16 h = (_Float16)v;
        hi[j] = h;
        lo[j] = (_Float16)((v - (float)h) * 2048.0f);
      }
      Whi[nt][kt] = hi; Wlo[nt][kt] = lo;
    }
  }
  const int n_sel = wv*32 + sel*16 + q*4;    // this lane's 4 finalized columns
  const float4v gmr = *reinterpret_cast<const float4v*>(&gma[n_sel]);
  __syncthreads();                            // wg/gb/xi ready, buffers zeroed
  const float4v wgr = *reinterpret_cast<const float4v*>(&sm.wg[n_sel]);

  const float c1 = 4.8828125e-4f;             // 2^-11
  const float* gbp = &sm.gb[0][n_sel];
  float4v th4;                                // last tanh outputs (epilogue)

  // software prefetch: x-index and gb bias row for step t are issued >=1 full
  // step before their use, so their LDS latency is always covered.
  int     xv_n  = sm.xi[r][0];
  float4v gbv_n = *reinterpret_cast<const float4v*>(gbp + xv_n*268);

  #pragma unroll 2
  for (int t = 0; t < T_STEPS; ++t) {
    const int rb = t & 1, wb = rb ^ 1;

    // issue red reads NOW, consume after the MFMA loop (latency overlapped)
    const float* rp = &sm.red[rb][r][0];
    const float4v ra  = *reinterpret_cast<const float4v*>(rp);
    const float4v rbv = *reinterpret_cast<const float4v*>(rp + 4);
    const float4v rc  = *reinterpret_cast<const float4v*>(rp + 8);
    const float4v rd  = *reinterpret_cast<const float4v*>(rp + 12);

    const float4v gbv = gbv_n;                 // bias row for THIS step
    const int xv2 = sm.xi[r][t + 1];           // prefetch next x index

    // MFMA phase: full K; B-fragments broadcast-read from row r
    const _Float16* ph = &sm.Ah[rb][r][0];
    const _Float16* pl = &sm.Al[rb][r][0];
    float4v a0[2], a1a[2], a1b[2];
    a0[0] = 0.0f; a0[1] = 0.0f;
    a1a[0] = 0.0f; a1a[1] = 0.0f;
    a1b[0] = 0.0f; a1b[1] = 0.0f;
    #pragma unroll
    for (int kt = 0; kt < 8; ++kt) {
      const half8 bhi = *reinterpret_cast<const half8*>(ph + kt*32 + q*8);
      const half8 blo = *reinterpret_cast<const half8*>(pl + kt*32 + q*8);
      a0[0]  = __builtin_amdgcn_mfma_f32_16x16x32_f16(Whi[0][kt], bhi, a0[0],  0, 0, 0);
      a0[1]  = __builtin_amdgcn_mfma_f32_16x16x32_f16(Whi[1][kt], bhi, a0[1],  0, 0, 0);
      a1a[0] = __builtin_amdgcn_mfma_f32_16x16x32_f16(Wlo[0][kt], bhi, a1a[0], 0, 0, 0);
      a1a[1] = __builtin_amdgcn_mfma_f32_16x16x32_f16(Wlo[1][kt], bhi, a1a[1], 0, 0, 0);
      a1b[0] = __builtin_amdgcn_mfma_f32_16x16x32_f16(Whi[0][kt], blo, a1b[0], 0, 0, 0);
      a1b[1] = __builtin_amdgcn_mfma_f32_16x16x32_f16(Whi[1][kt], blo, a1b[1], 0, 0, 0);
    }

    // prefetch gb row for step t+1 (consumed next iteration)
    gbv_n = *reinterpret_cast<const float4v*>(gbp + xv2*268);

    // LN stats of th(t-1): math here so red-load latency hid under MFMAs
    const float S  = ((ra[0]+ra[1])+(ra[2]+ra[3])) + ((rbv[0]+rbv[1])+(rbv[2]+rbv[3]));
    const float Sq = ((rc[0]+rc[1])+(rc[2]+rc[3])) + ((rd[0]+rd[1])+(rd[2]+rd[3]));
    const float mu  = S * (1.0f/256.0f);
    const float var = fmaf(Sq, 1.0f/256.0f, -mu*mu);
    const float rs  = __builtin_amdgcn_rsqf(var + LN_EPS);
    const float nrsmu = -rs * mu;
    const float rsc   = rs * c1;

    // tail (dedup): each lane finalizes 4 elements of row r, subtile sel
    float4v A0, A1;
    if (sel) { A0 = a0[1]; A1 = a1a[1] + a1b[1]; }
    else     { A0 = a0[0]; A1 = a1a[0] + a1b[0]; }
    float s = 0.0f, sq = 0.0f;
    half4v hi4, lo4;
    #pragma unroll
    for (int e = 0; e < 4; ++e) {
      const float base = fmaf(nrsmu, wgr[e], gbv[e]);
      const float pre  = fmaf(A0[e], rs, fmaf(A1[e], rsc, base));
      const float th   = tanh_fast(pre);
      th4[e] = th; s += th; sq = fmaf(th, th, sq);
      const float g2 = th * gmr[e];
      const _Float16 h16 = (_Float16)g2;
      hi4[e] = h16;
      lo4[e] = (_Float16)((g2 - (float)h16) * 2048.0f);
    }
    s  += __shfl_xor(s, 8, 64);  s  += __shfl_xor(s, 16, 64);  s  += __shfl_xor(s, 32, 64);
    sq += __shfl_xor(sq, 8, 64); sq += __shfl_xor(sq, 16, 64); sq += __shfl_xor(sq, 32, 64);

    *reinterpret_cast<half4v*>(&sm.Ah[wb][r][n_sel]) = hi4;
    *reinterpret_cast<half4v*>(&sm.Al[wb][r][n_sel]) = lo4;
    if (l < 8) { sm.red[wb][l][wv] = s; sm.red[wb][l][8 + wv] = sq; }
    xv_n = xv2;
    __syncthreads();                           // the ONLY barrier per step
  }

  // ---- epilogue: final LN (stats in red[0]), h_final in gb space, out GEMM ----
  float mu, rs;
  {
    const float* rp = &sm.red[0][r][0];
    const float4v ra  = *reinterpret_cast<const float4v*>(rp);
    const float4v rbv = *reinterpret_cast<const float4v*>(rp + 4);
    const float4v rc  = *reinterpret_cast<const float4v*>(rp + 8);
    const float4v rd  = *reinterpret_cast<const float4v*>(rp + 12);
    const float S  = ((ra[0]+ra[1])+(ra[2]+ra[3])) + ((rbv[0]+rbv[1])+(rbv[2]+rbv[3]));
    const float Sq = ((rc[0]+rc[1])+(rc[2]+rc[3])) + ((rd[0]+rd[1])+(rd[2]+rd[3]));
    mu = S * (1.0f/256.0f);
    const float var = fmaf(Sq, 1.0f/256.0f, -mu*mu);
    rs = __builtin_amdgcn_rsqf(var + LN_EPS);
  }
  float* hf = reinterpret_cast<float*>(&sm.gb[0][0]);   // gb dead after loop
  {
    const float4v btv = *reinterpret_cast<const float4v*>(&bta[n_sel]);
    float4v h4;
    #pragma unroll
    for (int e = 0; e < 4; ++e)
      h4[e] = fmaf((th4[e] - mu) * rs, gmr[e], btv[e]);
    *reinterpret_cast<float4v*>(&hf[r*260 + n_sel]) = h4;
  }
  __syncthreads();
  if (tid < ROWS*10) {
    const int rr = tid / 10, o = tid % 10;
    float acc = bo[o];
    #pragma unroll 4
    for (int n = 0; n < HDIM; ++n)
      acc = fmaf(hf[rr*260 + n], Wo[n*10 + o], acc);
    out[(size_t)(r0 + rr)*10 + o] = acc;
  }
}

extern "C" void kernel_launch(void* const* d_in, const int* in_sizes, int n_in,
                              void* d_out, int out_size, void* d_ws, size_t ws_size,
                              hipStream_t stream) {
  const float* x  = (const float*)d_in[0];
  const float* we = (const float*)d_in[1];
  const float* be = (const float*)d_in[2];
  const float* Wu = (const float*)d_in[3];
  const float* bu = (const float*)d_in[4];
  const float* ga = (const float*)d_in[5];
  const float* bt = (const float*)d_in[6];
  const float* Wo = (const float*)d_in[7];
  const float* bo = (const float*)d_in[8];
  const int B = in_sizes[0] / T_STEPS;          // 2048
  dim3 grid(B / ROWS), block(512);
  rnn_scan_kernel<<<grid, block, 0, stream>>>(x, we, be, Wu, bu, ga, bt, Wo, bo,
                                              (float*)d_out);
}

// Round 2
// 642.924 us; speedup vs baseline: 1.2315x; 1.2315x over previous
//
#include <hip/hip_runtime.h>
#include <hip/hip_fp16.h>
#include <cstdint>

#define T_STEPS 512
#define HDIM    256
#define ROWS    8
#define LN_EPS  1e-5f

typedef _Float16 half8   __attribute__((ext_vector_type(8)));
typedef _Float16 half4v  __attribute__((ext_vector_type(4)));
typedef float    float4v __attribute__((ext_vector_type(4)));
typedef float    float2v __attribute__((ext_vector_type(2)));

// R1 rewrite: packed hi|lo B-fragment.
// B tile cols 0..7 = fp16-hi of rows 0..7, cols 8..15 = fp16-lo rows 0..7.
// -> 4 MFMAs/kt (was 6), 1 lane-linear ds_read_b128/kt (was 2 conflicted),
//    one DPP xor-8 exchange reassembles hi/lo column products per output.
// All LDS shuffles removed from the LN reduction: xor8 = DPP row_ror:8 (VALU),
// xor16 = ds_swizzle, xor32 level replaced by 2 half-wave partials in red.
// Bp layout (halves): [buf][kt*512 + q*128 + c*8 + j]; read = lane-linear
// (lane l @ kt*1024 + l*16 bytes, conflict-free); write from tail:
// n -> (kt=n>>5, q'=(n>>3)&3, j=n&7), c = r (hi) / r+8 (lo).
struct __align__(16) Smem {
  _Float16 Bp[2][4096];     // 16384 B packed B fragments (double-buffered)
  float    gb[10][268];     // 10720 B gb[v][n] = tanh(v*we+be)@W + bu + beta@W
  float    wg[260];         // 1040 B  gamma @ W (deferred-LN mu term)
  float    wb[260];         // 1040 B  beta @ W
  float    red[2][8][36];   // 2304 B  [buf][row][slot*2+{0:S,1:Sq}], 16 slots
  int      xi[8][516];      // 16512 B clamped x indices (+pad col)
};

__device__ __forceinline__ float tanh_fast(float x) {
  float e = __expf(2.0f * x);
  float r = __builtin_amdgcn_rcpf(e + 1.0f);
  return fmaf(-2.0f, r, 1.0f);
}
// lane l -> l^8 (rotate-by-8 within each 16-lane row == xor 8), pure VALU
__device__ __forceinline__ float dpp_ror8(float v) {
  return __int_as_float(__builtin_amdgcn_mov_dpp(__float_as_int(v), 0x128, 0xf, 0xf, true));
}
// lane l -> l^16 (within 32-lane half), LDS crossbar, conflict-free
__device__ __forceinline__ float swz_xor16(float v) {
  return __int_as_float(__builtin_amdgcn_ds_swizzle(__float_as_int(v), 0x401F));
}

__global__ __launch_bounds__(512, 1)
void rnn_scan_kernel(const float* __restrict__ x,
                     const float* __restrict__ we,  const float* __restrict__ be,
                     const float* __restrict__ Wu,  const float* __restrict__ bu,
                     const float* __restrict__ gma, const float* __restrict__ bta,
                     const float* __restrict__ Wo,  const float* __restrict__ bo,
                     float* __restrict__ out)
{
  __shared__ Smem sm;
  const int tid = threadIdx.x;
  const int wv  = tid >> 6;        // wave 0..7, owns n in [32*wv, 32*wv+32)
  const int l   = tid & 63;
  const int q   = l >> 4;
  const int m   = l & 15;
  const int sel = m >> 3;          // 0: finalize nt=0 (hi cols), 1: nt=1
  const int r   = m & 7;           // batch row within tile
  const int r0  = blockIdx.x * ROWS;

  // ---- init 0: x -> clamped int indices in LDS (the ONLY x reads) ----
  for (int i = tid; i < ROWS * T_STEPS; i += 512) {
    const int rr = i >> 9, c = i & (T_STEPS - 1);
    int xv = (int)x[(size_t)(r0 + rr) * T_STEPS + c];
    xv = xv < 0 ? 0 : (xv > 9 ? 9 : xv);
    sm.xi[rr][c] = xv;
  }
  if (tid < ROWS) sm.xi[tid][T_STEPS] = 0;   // t+1 prefetch pad

  // ---- init 1: embed-tanh table in (to-be-zeroed) Bp space ----
  float* et = reinterpret_cast<float*>(&sm.Bp[0][0]);   // 10240 B < 16384 B
  if (tid < HDIM) {
    const float wek = we[tid], bek = be[tid];
    #pragma unroll
    for (int v = 0; v < 10; ++v)
      et[v*HDIM + tid] = tanh_fast(fmaf((float)v, wek, bek));
  }
  __syncthreads();

  // ---- init 2: gb = et@W + bu ; wg = gamma@W ; wb = beta@W ----
  {
    const int g = tid >> 8;        // 0: v=0..4 + wg, 1: v=5..9 + wb
    const int n = tid & 255;
    float acc[5] = {0,0,0,0,0};
    float accx = 0.0f;
    const int vb = g * 5;
    for (int k = 0; k < HDIM; ++k) {
      const float wk = Wu[(size_t)k*HDIM + n];
      #pragma unroll
      for (int v = 0; v < 5; ++v) acc[v] = fmaf(et[(vb+v)*HDIM + k], wk, acc[v]);
      const float xk = g ? bta[k] : gma[k];
      accx = fmaf(xk, wk, accx);
    }
    const float bun = bu[n];
    #pragma unroll
    for (int v = 0; v < 5; ++v) sm.gb[vb+v][n] = acc[v] + bun;
    if (g == 0) sm.wg[n] = accx; else sm.wb[n] = accx;
  }
  __syncthreads();

  // ---- init 3: fold beta@W into gb; zero Bp (both bufs) and red ----
  if (tid < HDIM) {
    const float wbn = sm.wb[tid];
    #pragma unroll
    for (int v = 0; v < 10; ++v) sm.gb[v][tid] += wbn;
  }
  {
    uint32_t* p = reinterpret_cast<uint32_t*>(&sm.Bp[0][0]);
    for (int i = tid; i < 4096; i += 512) p[i] = 0u;      // 16 KB = both bufs
  }
  for (int i = tid; i < 576; i += 512) (&sm.red[0][0][0])[i] = 0.0f;

  // ---- persistent W fragments: full K, this wave's two 16-wide n-tiles ----
  half8 Whi[2][8], Wlo[2][8];
  #pragma unroll
  for (int nt = 0; nt < 2; ++nt) {
    const int n = wv*32 + nt*16 + m;
    #pragma unroll
    for (int kt = 0; kt < 8; ++kt) {
      const int k0 = kt*32 + q*8;
      half8 hi, lo;
      #pragma unroll
      for (int j = 0; j < 8; ++j) {
        float v = Wu[(size_t)(k0 + j)*HDIM + n];           // L2-hot across blocks
        _Float16 h = (_Float16)v;
        hi[j] = h;
        lo[j] = (_Float16)((v - (float)h) * 2048.0f);
      }
      Whi[nt][kt] = hi; Wlo[nt][kt] = lo;
    }
  }
  const int n_sel = wv*32 + sel*16 + q*4;    // this lane's 4 finalized columns
  const float4v gmr = *reinterpret_cast<const float4v*>(&gma[n_sel]);
  __syncthreads();                            // wg/gb/xi ready, buffers zeroed
  const float4v wgr = *reinterpret_cast<const float4v*>(&sm.wg[n_sel]);

  const float c1 = 4.8828125e-4f;             // 2^-11
  const float* gbp = &sm.gb[0][n_sel];
  float4v th4;                                // last tanh outputs (epilogue)

  // per-lane constant LDS offsets (halves)
  const int rdoff = l * 8;                                        // B read base
  const int woff  = wv*512 + (2*sel + (q>>1))*128 + r*8 + (q&1)*4; // hi write; lo at +64

  // software prefetch: x-index and gb bias row issued >=1 step ahead
  int     xv_n  = sm.xi[r][0];
  float4v gbv_n = *reinterpret_cast<const float4v*>(gbp + xv_n*268);

  #pragma unroll 2
  for (int t = 0; t < T_STEPS; ++t) {
    const int rb = t & 1, wb = rb ^ 1;

    // issue red reads NOW, consume after the MFMA loop (latency overlapped)
    const float* rp = &sm.red[rb][r][0];
    const float4v p0 = *reinterpret_cast<const float4v*>(rp);
    const float4v p1 = *reinterpret_cast<const float4v*>(rp + 4);
    const float4v p2 = *reinterpret_cast<const float4v*>(rp + 8);
    const float4v p3 = *reinterpret_cast<const float4v*>(rp + 12);
    const float4v p4 = *reinterpret_cast<const float4v*>(rp + 16);
    const float4v p5 = *reinterpret_cast<const float4v*>(rp + 20);
    const float4v p6 = *reinterpret_cast<const float4v*>(rp + 24);
    const float4v p7 = *reinterpret_cast<const float4v*>(rp + 28);

    const float4v gbv = gbv_n;                 // bias row for THIS step
    const int xv2 = sm.xi[r][t + 1];           // prefetch next x index

    // MFMA phase: 1 lane-linear b128 read + 4 MFMAs per kt
    const _Float16* pbB = &sm.Bp[rb][rdoff];
    float4v d10, d11, d20, d21;
    d10 = 0.0f; d11 = 0.0f; d20 = 0.0f; d21 = 0.0f;
    #pragma unroll
    for (int kt = 0; kt < 8; ++kt) {
      const half8 b = *reinterpret_cast<const half8*>(pbB + kt*512);
      d10 = __builtin_amdgcn_mfma_f32_16x16x32_f16(Whi[0][kt], b, d10, 0, 0, 0);
      d11 = __builtin_amdgcn_mfma_f32_16x16x32_f16(Whi[1][kt], b, d11, 0, 0, 0);
      d20 = __builtin_amdgcn_mfma_f32_16x16x32_f16(Wlo[0][kt], b, d20, 0, 0, 0);
      d21 = __builtin_amdgcn_mfma_f32_16x16x32_f16(Wlo[1][kt], b, d21, 0, 0, 0);
    }

    // prefetch gb row for step t+1 (consumed next iteration)
    gbv_n = *reinterpret_cast<const float4v*>(gbp + xv2*268);

    // LN stats of th(t-1): 16 interleaved {S,Sq} partials (in MFMA shadow)
    const float S  = (((p0[0]+p0[2])+(p1[0]+p1[2])) + ((p2[0]+p2[2])+(p3[0]+p3[2])))
                   + (((p4[0]+p4[2])+(p5[0]+p5[2])) + ((p6[0]+p6[2])+(p7[0]+p7[2])));
    const float Sq = (((p0[1]+p0[3])+(p1[1]+p1[3])) + ((p2[1]+p2[3])+(p3[1]+p3[3])))
                   + (((p4[1]+p4[3])+(p5[1]+p5[3])) + ((p6[1]+p6[3])+(p7[1]+p7[3])));
    const float mu  = S * (1.0f/256.0f);
    const float var = fmaf(Sq, 1.0f/256.0f, -mu*mu);
    const float rs  = __builtin_amdgcn_rsqf(var + LN_EPS);
    const float nrsmu = -rs * mu;
    const float rsc   = rs * c1;

    // tail: reassemble each output's 3 products from its two B columns.
    // sel=0 lanes (cols 0..7, hi products) finalize nt=0:
    //   local = rs*d10 + rsc*d20, partner sends rsc*d10(=Whi0*lo).
    // sel=1 lanes (cols 8..15, lo products) finalize nt=1:
    //   local = rsc*d11(=Whi1*lo), partner sends rs*d11 + rsc*d21 (hi terms).
    const float csA = sel ? rsc : rs;
    float4v sendv, locv;
    #pragma unroll
    for (int e = 0; e < 4; ++e) {
      const float pA = sel ? d10[e] : d11[e];
      const float pB = sel ? 0.0f   : d21[e];
      sendv[e] = fmaf(csA, pA, rsc * pB);
      const float qA = sel ? d11[e] : d10[e];
      const float qB = sel ? 0.0f   : d20[e];
      locv[e]  = fmaf(csA, qA, rsc * qB);
    }
    float4v recv;
    #pragma unroll
    for (int e = 0; e < 4; ++e) recv[e] = dpp_ror8(sendv[e]);

    float s = 0.0f, sq = 0.0f;
    half4v hi4, lo4;
    #pragma unroll
    for (int e = 0; e < 4; ++e) {
      const float base = fmaf(nrsmu, wgr[e], gbv[e]);
      const float pre  = locv[e] + recv[e] + base;
      const float th   = tanh_fast(pre);
      th4[e] = th; s += th; sq = fmaf(th, th, sq);
      const float g2 = th * gmr[e];
      const _Float16 h16 = (_Float16)g2;
      hi4[e] = h16;
      lo4[e] = (_Float16)((g2 - (float)h16) * 2048.0f);
    }
    // reduce over sel (xor8, DPP) and q-pair (xor16, swizzle); the xor32
    // level is deferred: two half-wave partials per wave, summed next step.
    s  += dpp_ror8(s);  s  += swz_xor16(s);
    sq += dpp_ror8(sq); sq += swz_xor16(sq);

    _Float16* wp = &sm.Bp[wb][woff];
    *reinterpret_cast<half4v*>(wp)      = hi4;
    *reinterpret_cast<half4v*>(wp + 64) = lo4;
    if ((l & 31) < 8) {
      const int slot = wv*2 + (l >> 5);
      float2v v2; v2[0] = s; v2[1] = sq;
      *reinterpret_cast<float2v*>(&sm.red[wb][r][slot*2]) = v2;
    }
    xv_n = xv2;
    __syncthreads();                           // the ONLY barrier per step
  }

  // ---- epilogue: final LN (stats in red[0]), h_final in gb space, out GEMM ----
  float mu, rs;
  {
    const float* rp = &sm.red[0][r][0];
    const float4v p0 = *reinterpret_cast<const float4v*>(rp);
    const float4v p1 = *reinterpret_cast<const float4v*>(rp + 4);
    const float4v p2 = *reinterpret_cast<const float4v*>(rp + 8);
    const float4v p3 = *reinterpret_cast<const float4v*>(rp + 12);
    const float4v p4 = *reinterpret_cast<const float4v*>(rp + 16);
    const float4v p5 = *reinterpret_cast<const float4v*>(rp + 20);
    const float4v p6 = *reinterpret_cast<const float4v*>(rp + 24);
    const float4v p7 = *reinterpret_cast<const float4v*>(rp + 28);
    const float S  = (((p0[0]+p0[2])+(p1[0]+p1[2])) + ((p2[0]+p2[2])+(p3[0]+p3[2])))
                   + (((p4[0]+p4[2])+(p5[0]+p5[2])) + ((p6[0]+p6[2])+(p7[0]+p7[2])));
    const float Sq = (((p0[1]+p0[3])+(p1[1]+p1[3])) + ((p2[1]+p2[3])+(p3[1]+p3[3])))
                   + (((p4[1]+p4[3])+(p5[1]+p5[3])) + ((p6[1]+p6[3])+(p7[1]+p7[3])));
    mu = S * (1.0f/256.0f);
    const float var = fmaf(Sq, 1.0f/256.0f, -mu*mu);
    rs = __builtin_amdgcn_rsqf(var + LN_EPS);
  }
  float* hf = reinterpret_cast<float*>(&sm.gb[0][0]);   // gb dead after loop
  {
    const float4v btv = *reinterpret_cast<const float4v*>(&bta[n_sel]);
    float4v h4;
    #pragma unroll
    for (int e = 0; e < 4; ++e)
      h4[e] = fmaf((th4[e] - mu) * rs, gmr[e], btv[e]);
    *reinterpret_cast<float4v*>(&hf[r*260 + n_sel]) = h4;
  }
  __syncthreads();
  if (tid < ROWS*10) {
    const int rr = tid / 10, o = tid % 10;
    float acc = bo[o];
    #pragma unroll 4
    for (int n = 0; n < HDIM; ++n)
      acc = fmaf(hf[rr*260 + n], Wo[n*10 + o], acc);
    out[(size_t)(r0 + rr)*10 + o] = acc;
  }
}

extern "C" void kernel_launch(void* const* d_in, const int* in_sizes, int n_in,
                              void* d_out, int out_size, void* d_ws, size_t ws_size,
                              hipStream_t stream) {
  const float* x  = (const float*)d_in[0];
  const float* we = (const float*)d_in[1];
  const float* be = (const float*)d_in[2];
  const float* Wu = (const float*)d_in[3];
  const float* bu = (const float*)d_in[4];
  const float* ga = (const float*)d_in[5];
  const float* bt = (const float*)d_in[6];
  const float* Wo = (const float*)d_in[7];
  const float* bo = (const float*)d_in[8];
  const int B = in_sizes[0] / T_STEPS;          // 2048
  dim3 grid(B / ROWS), block(512);
  rnn_scan_kernel<<<grid, block, 0, stream>>>(x, we, be, Wu, bu, ga, bt, Wo, bo,
                                              (float*)d_out);
}

// Round 5
// 605.759 us; speedup vs baseline: 1.3071x; 1.0614x over previous
//
#include <hip/hip_runtime.h>
#include <hip/hip_fp16.h>
#include <cstdint>

#define T_STEPS 512
#define HDIM    256
#define ROWS    8
#define LN_EPS  1e-5f

typedef _Float16 half8   __attribute__((ext_vector_type(8)));
typedef _Float16 half4v  __attribute__((ext_vector_type(4)));
typedef float    float4v __attribute__((ext_vector_type(4)));
typedef float    float2v __attribute__((ext_vector_type(2)));

// R4: R1's verified 4-MFMA/kt numerics (hi*hi + hi*lo_act + lo_W*hi: all three
// terms REQUIRED -- measured recurrence amplifies per-step error ~1400x, so
// per-step budget is ~4e-5; R2's dropped term gave 5e-4/step -> absmax 0.67
// FAIL) + R2's halved red traffic: LN reduction completes in-wave
// (dpp xor8 + swizzle xor16 + shfl_xor32), red = 1 {S,Sq} slot/wave/row,
// consume = 4 b128 (was 8). xor32 uses __shfl_xor (ds_bpermute, known-correct)
// not the unverified permlane asm.
struct __align__(16) Smem {
  _Float16 Bp[2][4096];     // 16384 B packed B fragments (double-buffered)
  float    gb[10][268];     // 10720 B gb[v][n] = tanh(v*we+be)@W + bu + beta@W
  float    wg[260];         // 1040 B  gamma @ W (deferred-LN mu term)
  float    wb[260];         // 1040 B  beta @ W
  float    red[2][8][20];   // 1280 B  [buf][row][wv*2+{0:S,1:Sq}], 8 slots
  int      xi[8][516];      // 16512 B clamped x indices (+pad col)
};

__device__ __forceinline__ float tanh_fast(float x) {
  float e = __expf(2.0f * x);
  float r = __builtin_amdgcn_rcpf(e + 1.0f);
  return fmaf(-2.0f, r, 1.0f);
}
// lane l -> l^8 (rotate-by-8 within each 16-lane row == xor 8), pure VALU
__device__ __forceinline__ float dpp_ror8(float v) {
  return __int_as_float(__builtin_amdgcn_mov_dpp(__float_as_int(v), 0x128, 0xf, 0xf, true));
}
// lane l -> l^16 (within 32-lane half), LDS crossbar, conflict-free
__device__ __forceinline__ float swz_xor16(float v) {
  return __int_as_float(__builtin_amdgcn_ds_swizzle(__float_as_int(v), 0x401F));
}

__global__ __launch_bounds__(512, 1)
void rnn_scan_kernel(const float* __restrict__ x,
                     const float* __restrict__ we,  const float* __restrict__ be,
                     const float* __restrict__ Wu,  const float* __restrict__ bu,
                     const float* __restrict__ gma, const float* __restrict__ bta,
                     const float* __restrict__ Wo,  const float* __restrict__ bo,
                     float* __restrict__ out)
{
  __shared__ Smem sm;
  const int tid = threadIdx.x;
  const int wv  = tid >> 6;        // wave 0..7, owns n in [32*wv, 32*wv+32)
  const int l   = tid & 63;
  const int q   = l >> 4;
  const int m   = l & 15;
  const int sel = m >> 3;          // 0: finalize nt=0 (hi cols), 1: nt=1
  const int r   = m & 7;           // batch row within tile
  const int r0  = blockIdx.x * ROWS;

  // ---- init 0: x -> clamped int indices in LDS (the ONLY x reads) ----
  for (int i = tid; i < ROWS * T_STEPS; i += 512) {
    const int rr = i >> 9, c = i & (T_STEPS - 1);
    int xv = (int)x[(size_t)(r0 + rr) * T_STEPS + c];
    xv = xv < 0 ? 0 : (xv > 9 ? 9 : xv);
    sm.xi[rr][c] = xv;
  }
  if (tid < ROWS) sm.xi[tid][T_STEPS] = 0;   // t+1 prefetch pad

  // ---- init 1: embed-tanh table in (to-be-zeroed) Bp space ----
  float* et = reinterpret_cast<float*>(&sm.Bp[0][0]);   // 10240 B < 16384 B
  if (tid < HDIM) {
    const float wek = we[tid], bek = be[tid];
    #pragma unroll
    for (int v = 0; v < 10; ++v)
      et[v*HDIM + tid] = tanh_fast(fmaf((float)v, wek, bek));
  }
  __syncthreads();

  // ---- init 2: gb = et@W + bu ; wg = gamma@W ; wb = beta@W ----
  {
    const int g = tid >> 8;        // 0: v=0..4 + wg, 1: v=5..9 + wb
    const int n = tid & 255;
    float acc[5] = {0,0,0,0,0};
    float accx = 0.0f;
    const int vb = g * 5;
    for (int k = 0; k < HDIM; ++k) {
      const float wk = Wu[(size_t)k*HDIM + n];
      #pragma unroll
      for (int v = 0; v < 5; ++v) acc[v] = fmaf(et[(vb+v)*HDIM + k], wk, acc[v]);
      const float xk = g ? bta[k] : gma[k];
      accx = fmaf(xk, wk, accx);
    }
    const float bun = bu[n];
    #pragma unroll
    for (int v = 0; v < 5; ++v) sm.gb[vb+v][n] = acc[v] + bun;
    if (g == 0) sm.wg[n] = accx; else sm.wb[n] = accx;
  }
  __syncthreads();

  // ---- init 3: fold beta@W into gb; zero Bp (both bufs) and red ----
  if (tid < HDIM) {
    const float wbn = sm.wb[tid];
    #pragma unroll
    for (int v = 0; v < 10; ++v) sm.gb[v][tid] += wbn;
  }
  {
    uint32_t* p = reinterpret_cast<uint32_t*>(&sm.Bp[0][0]);
    for (int i = tid; i < 4096; i += 512) p[i] = 0u;      // 16 KB = both bufs
  }
  if (tid < 320) (&sm.red[0][0][0])[tid] = 0.0f;

  // ---- persistent W fragments: full K, this wave's two 16-wide n-tiles ----
  half8 Whi[2][8], Wlo[2][8];
  #pragma unroll
  for (int nt = 0; nt < 2; ++nt) {
    const int n = wv*32 + nt*16 + m;
    #pragma unroll
    for (int kt = 0; kt < 8; ++kt) {
      const int k0 = kt*32 + q*8;
      half8 hi, lo;
      #pragma unroll
      for (int j = 0; j < 8; ++j) {
        float v = Wu[(size_t)(k0 + j)*HDIM + n];           // L2-hot across blocks
        _Float16 h = (_Float16)v;
        hi[j] = h;
        lo[j] = (_Float16)((v - (float)h) * 2048.0f);
      }
      Whi[nt][kt] = hi; Wlo[nt][kt] = lo;
    }
  }
  const int n_sel = wv*32 + sel*16 + q*4;    // this lane's 4 finalized columns
  const float4v gmr = *reinterpret_cast<const float4v*>(&gma[n_sel]);
  __syncthreads();                            // wg/gb/xi ready, buffers zeroed
  const float4v wgr = *reinterpret_cast<const float4v*>(&sm.wg[n_sel]);

  const float c1 = 4.8828125e-4f;             // 2^-11
  const float* gbp = &sm.gb[0][n_sel];
  float4v th4;                                // last tanh outputs (epilogue)

  // per-lane constant LDS offsets (halves)
  const int rdoff = l * 8;                                        // B read base
  const int woff  = wv*512 + (2*sel + (q>>1))*128 + r*8 + (q&1)*4; // hi write; lo at +64

  // software prefetch: x-index and gb bias row issued >=1 step ahead
  int     xv_n  = sm.xi[r][0];
  float4v gbv_n = *reinterpret_cast<const float4v*>(gbp + xv_n*268);

  #pragma unroll 2
  for (int t = 0; t < T_STEPS; ++t) {
    const int rb = t & 1, wb = rb ^ 1;

    // issue red reads NOW, consume after the MFMA loop (latency overlapped)
    const float* rp = &sm.red[rb][r][0];
    const float4v p0 = *reinterpret_cast<const float4v*>(rp);
    const float4v p1 = *reinterpret_cast<const float4v*>(rp + 4);
    const float4v p2 = *reinterpret_cast<const float4v*>(rp + 8);
    const float4v p3 = *reinterpret_cast<const float4v*>(rp + 12);

    const float4v gbv = gbv_n;                 // bias row for THIS step
    const int xv2 = sm.xi[r][t + 1];           // prefetch next x index

    // MFMA phase: 1 lane-linear b128 read + 4 MFMAs per kt
    const _Float16* pbB = &sm.Bp[rb][rdoff];
    float4v d10, d11, d20, d21;
    d10 = 0.0f; d11 = 0.0f; d20 = 0.0f; d21 = 0.0f;
    #pragma unroll
    for (int kt = 0; kt < 8; ++kt) {
      const half8 b = *reinterpret_cast<const half8*>(pbB + kt*512);
      d10 = __builtin_amdgcn_mfma_f32_16x16x32_f16(Whi[0][kt], b, d10, 0, 0, 0);
      d11 = __builtin_amdgcn_mfma_f32_16x16x32_f16(Whi[1][kt], b, d11, 0, 0, 0);
      d20 = __builtin_amdgcn_mfma_f32_16x16x32_f16(Wlo[0][kt], b, d20, 0, 0, 0);
      d21 = __builtin_amdgcn_mfma_f32_16x16x32_f16(Wlo[1][kt], b, d21, 0, 0, 0);
    }

    // prefetch gb row for step t+1 (consumed next iteration)
    gbv_n = *reinterpret_cast<const float4v*>(gbp + xv2*268);

    // LN stats of th(t-1): 8 interleaved {S,Sq} wave-partials (in MFMA shadow)
    const float S  = ((p0[0]+p0[2]) + (p1[0]+p1[2])) + ((p2[0]+p2[2]) + (p3[0]+p3[2]));
    const float Sq = ((p0[1]+p0[3]) + (p1[1]+p1[3])) + ((p2[1]+p2[3]) + (p3[1]+p3[3]));
    const float mu  = S * (1.0f/256.0f);
    const float var = fmaf(Sq, 1.0f/256.0f, -mu*mu);
    const float rs  = __builtin_amdgcn_rsqf(var + LN_EPS);
    const float nrsmu = -rs * mu;
    const float rsc   = rs * c1;

    // tail: reassemble each output's 3 products from its two B columns.
    // sel=0 lanes (cols 0..7, hi products) finalize nt=0:
    //   local = rs*d10 + rsc*d20, partner sends rsc*d10 (=Whi0*lo_act).
    // sel=1 lanes (cols 8..15, lo products) finalize nt=1:
    //   local = rsc*d11 (=Whi1*lo_act), partner sends rs*d11 + rsc*d21.
    const float csA = sel ? rsc : rs;
    float4v sendv, locv;
    #pragma unroll
    for (int e = 0; e < 4; ++e) {
      const float pA = sel ? d10[e] : d11[e];
      const float pB = sel ? 0.0f   : d21[e];
      sendv[e] = fmaf(csA, pA, rsc * pB);
      const float qA = sel ? d11[e] : d10[e];
      const float qB = sel ? 0.0f   : d20[e];
      locv[e]  = fmaf(csA, qA, rsc * qB);
    }
    float4v recv;
    #pragma unroll
    for (int e = 0; e < 4; ++e) recv[e] = dpp_ror8(sendv[e]);

    float s = 0.0f, sq = 0.0f;
    half4v hi4, lo4;
    #pragma unroll
    for (int e = 0; e < 4; ++e) {
      const float base = fmaf(nrsmu, wgr[e], gbv[e]);
      const float pre  = locv[e] + recv[e] + base;
      const float th   = tanh_fast(pre);
      th4[e] = th; s += th; sq = fmaf(th, th, sq);
      const float g2 = th * gmr[e];
      const _Float16 h16 = (_Float16)g2;
      hi4[e] = h16;
      lo4[e] = (_Float16)((g2 - (float)h16) * 2048.0f);
    }
    // full in-wave reduction: xor8 (DPP) + xor16 (swizzle) + xor32 (bpermute)
    s  += dpp_ror8(s);  s  += swz_xor16(s);  s  += __shfl_xor(s, 32, 64);
    sq += dpp_ror8(sq); sq += swz_xor16(sq); sq += __shfl_xor(sq, 32, 64);

    _Float16* wp = &sm.Bp[wb][woff];
    *reinterpret_cast<half4v*>(wp)      = hi4;
    *reinterpret_cast<half4v*>(wp + 64) = lo4;
    if (l < 8) {
      float2v v2; v2[0] = s; v2[1] = sq;
      *reinterpret_cast<float2v*>(&sm.red[wb][l][wv*2]) = v2;
    }
    xv_n = xv2;
    __syncthreads();                           // the ONLY barrier per step
  }

  // ---- epilogue: final LN (stats in red[0]), h_final in gb space, out GEMM ----
  float mu, rs;
  {
    const float* rp = &sm.red[0][r][0];
    const float4v p0 = *reinterpret_cast<const float4v*>(rp);
    const float4v p1 = *reinterpret_cast<const float4v*>(rp + 4);
    const float4v p2 = *reinterpret_cast<const float4v*>(rp + 8);
    const float4v p3 = *reinterpret_cast<const float4v*>(rp + 12);
    const float S  = ((p0[0]+p0[2]) + (p1[0]+p1[2])) + ((p2[0]+p2[2]) + (p3[0]+p3[2]));
    const float Sq = ((p0[1]+p0[3]) + (p1[1]+p1[3])) + ((p2[1]+p2[3]) + (p3[1]+p3[3]));
    mu = S * (1.0f/256.0f);
    const float var = fmaf(Sq, 1.0f/256.0f, -mu*mu);
    rs = __builtin_amdgcn_rsqf(var + LN_EPS);
  }
  float* hf = reinterpret_cast<float*>(&sm.gb[0][0]);   // gb dead after loop
  {
    const float4v btv = *reinterpret_cast<const float4v*>(&bta[n_sel]);
    float4v h4;
    #pragma unroll
    for (int e = 0; e < 4; ++e)
      h4[e] = fmaf((th4[e] - mu) * rs, gmr[e], btv[e]);
    *reinterpret_cast<float4v*>(&hf[r*260 + n_sel]) = h4;
  }
  __syncthreads();
  if (tid < ROWS*10) {
    const int rr = tid / 10, o = tid % 10;
    float acc = bo[o];
    #pragma unroll 4
    for (int n = 0; n < HDIM; ++n)
      acc = fmaf(hf[rr*260 + n], Wo[n*10 + o], acc);
    out[(size_t)(r0 + rr)*10 + o] = acc;
  }
}

extern "C" void kernel_launch(void* const* d_in, const int* in_sizes, int n_in,
                              void* d_out, int out_size, void* d_ws, size_t ws_size,
                              hipStream_t stream) {
  const float* x  = (const float*)d_in[0];
  const float* we = (const float*)d_in[1];
  const float* be = (const float*)d_in[2];
  const float* Wu = (const float*)d_in[3];
  const float* bu = (const float*)d_in[4];
  const float* ga = (const float*)d_in[5];
  const float* bt = (const float*)d_in[6];
  const float* Wo = (const float*)d_in[7];
  const float* bo = (const float*)d_in[8];
  const int B = in_sizes[0] / T_STEPS;          // 2048
  dim3 grid(B / ROWS), block(512);
  rnn_scan_kernel<<<grid, block, 0, stream>>>(x, we, be, Wu, bu, ga, bt, Wo, bo,
                                              (float*)d_out);
}